// Round 1
// baseline (2506.846 us; speedup 1.0000x reference)
//
#include <hip/hip_runtime.h>

typedef unsigned short u16;
typedef unsigned int u32;

#define N_NODES 20000
#define N_EDGES 320000
#define FEAT 100
#define XPAD 112   // padded cols for bf16 node mirrors (14 x 16B rows)
#define MPAD 104   // padded cols for bf16 message buffer (13 x 16B rows)
#define N_RULES 64
#define T_RULE 50
#define H_RNN 256
#define RULE_NUMS 16
#define NTN_OUT 200

typedef __attribute__((ext_vector_type(8))) short short8;
typedef __attribute__((ext_vector_type(4))) float f32x4;

__device__ __forceinline__ u16 f2bu(float f) {
  u32 u = __float_as_uint(f);
  u32 r = (u + 0x7fffu + ((u >> 16) & 1u)) >> 16;   // RNE
  return (u16)r;
}
__device__ __forceinline__ float bu2f(u16 u) {
  return __uint_as_float(((u32)u) << 16);
}
__device__ __forceinline__ u32 pk2(float a, float b) {
  return (u32)f2bu(a) | ((u32)f2bu(b) << 16);
}

__device__ __forceinline__ void lds_st16(void* base, int byteOff, uint4 v) {
  *(uint4*)((char*)base + byteOff) = v;
}
__device__ __forceinline__ short8 lds_ld16(const void* base, int byteOff) {
  return *(const short8*)((const char*)base + byteOff);
}

// XOR swizzle: rows of 256B (128 bf16), flip bits 4..6 by row&7 (G4 / T2)
#define SWZ(row, kByte) (((((row) << 8) + (kByte))) ^ (((row) & 7) << 4))

// ---------------------------------------------------------------- prep: bf16 mirrors
__global__ void k_prep(const float* __restrict__ nf0, const float* __restrict__ nf1,
                       u16* __restrict__ xb0, u16* __restrict__ xb1) {
  const int total = N_NODES * XPAD;
  for (int i = blockIdx.x * blockDim.x + threadIdx.x; i < total;
       i += gridDim.x * blockDim.x) {
    const int n = i / XPAD;
    const int c = i - n * XPAD;
    const float v0 = (c < FEAT) ? nf0[(size_t)n * FEAT + c] : 0.f;
    const float v1 = (c < FEAT) ? nf1[(size_t)n * FEAT + c] : 0.f;
    xb0[i] = f2bu(v0);
    xb1[i] = f2bu(v1);
  }
}

// ---------------------------------------------------------------- CSR build
__global__ void k_count(const int* __restrict__ dstI, int* __restrict__ cnt) {
  const int e = blockIdx.x * blockDim.x + threadIdx.x;
  if (e < N_EDGES) atomicAdd(&cnt[dstI[e]], 1);
}

__global__ __launch_bounds__(1024) void k_scan(int* cnt /*in: counts, out: cursor*/,
                                               int* off) {
  __shared__ int buf[1024];
  __shared__ int carry;
  const int tid = threadIdx.x;
  if (tid == 0) carry = 0;
  __syncthreads();
  for (int base = 0; base < N_NODES; base += 1024) {
    const int i = base + tid;
    const int v = (i < N_NODES) ? cnt[i] : 0;
    buf[tid] = v;
    __syncthreads();
    for (int ofs = 1; ofs < 1024; ofs <<= 1) {
      const int t = (tid >= ofs) ? buf[tid - ofs] : 0;
      __syncthreads();
      buf[tid] += t;
      __syncthreads();
    }
    const int incl = buf[tid];
    const int chunkTotal = buf[1023];
    const int cb = carry;
    __syncthreads();
    if (i < N_NODES) {
      const int excl = cb + incl - v;
      off[i] = excl;
      cnt[i] = excl;   // cursor for scatter
    }
    if (tid == 0) carry = cb + chunkTotal;
    __syncthreads();
  }
  if (tid == 0) off[N_NODES] = carry;
}

__global__ void k_scatter(const int* __restrict__ dstI, int* __restrict__ cursor,
                          int* __restrict__ elist) {
  const int e = blockIdx.x * blockDim.x + threadIdx.x;
  if (e < N_EDGES) {
    const int pos = atomicAdd(&cursor[dstI[e]], 1);
    elist[pos] = e;
  }
}

// ---------------------------------------------------------------- RNN (1 block / rule)
__global__ __launch_bounds__(512) void k_rnn(
    const float* __restrict__ rules,
    const float* __restrict__ Wih0, const float* __restrict__ Whh0,
    const float* __restrict__ bih0, const float* __restrict__ bhh0,
    const float* __restrict__ Wih1, const float* __restrict__ Whh1,
    const float* __restrict__ bih1, const float* __restrict__ bhh1,
    const float* __restrict__ rlW, const float* __restrict__ rlb,
    float* __restrict__ emb) {
  __shared__ __align__(16) float xs[FEAT];
  __shared__ __align__(16) float h0[H_RNN];
  __shared__ __align__(16) float h1[H_RNN];
  __shared__ float part[512];
  const int b = blockIdx.x;
  const int tid = threadIdx.x;
  const int j = tid & 255;
  const int half = tid >> 8;
  if (tid < H_RNN) { h0[tid] = 0.f; h1[tid] = 0.f; }
  for (int t = 0; t < T_RULE; ++t) {
    __syncthreads();
    if (tid < FEAT) xs[tid] = rules[((size_t)b * T_RULE + t) * FEAT + tid];
    __syncthreads();
    // ---- layer 0:  s = bih0 + bhh0 + Wih0[j]*x + Whh0[j]*h0
    float s;
    if (half == 0) {
      s = bih0[j] + bhh0[j];
      const float4* w = (const float4*)(Wih0 + (size_t)j * FEAT);
      const float4* xv = (const float4*)xs;
#pragma unroll 5
      for (int k = 0; k < 25; ++k) {
        const float4 a = w[k], x = xv[k];
        s += a.x * x.x + a.y * x.y + a.z * x.z + a.w * x.w;
      }
      const float4* wh = (const float4*)(Whh0 + (size_t)j * H_RNN);
      const float4* hv = (const float4*)h0;
#pragma unroll 8
      for (int k = 0; k < 32; ++k) {
        const float4 a = wh[k], x = hv[k];
        s += a.x * x.x + a.y * x.y + a.z * x.z + a.w * x.w;
      }
    } else {
      s = 0.f;
      const float4* wh = (const float4*)(Whh0 + (size_t)j * H_RNN);
      const float4* hv = (const float4*)h0;
#pragma unroll 8
      for (int k = 32; k < 64; ++k) {
        const float4 a = wh[k], x = hv[k];
        s += a.x * x.x + a.y * x.y + a.z * x.z + a.w * x.w;
      }
    }
    part[tid] = s;
    __syncthreads();
    float y0 = 0.f;
    if (half == 0) y0 = tanhf(part[j] + part[j + 256]);
    __syncthreads();
    if (half == 0) h0[j] = y0;
    __syncthreads();
    // ---- layer 1:  s1 = bih1 + bhh1 + Wih1[j]*h0new + Whh1[j]*h1
    float s1;
    if (half == 0) {
      s1 = bih1[j] + bhh1[j];
      const float4* w = (const float4*)(Wih1 + (size_t)j * H_RNN);
      const float4* hv = (const float4*)h0;
#pragma unroll 8
      for (int k = 0; k < 64; ++k) {
        const float4 a = w[k], x = hv[k];
        s1 += a.x * x.x + a.y * x.y + a.z * x.z + a.w * x.w;
      }
    } else {
      s1 = 0.f;
      const float4* wh = (const float4*)(Whh1 + (size_t)j * H_RNN);
      const float4* hv = (const float4*)h1;
#pragma unroll 8
      for (int k = 0; k < 64; ++k) {
        const float4 a = wh[k], x = hv[k];
        s1 += a.x * x.x + a.y * x.y + a.z * x.z + a.w * x.w;
      }
    }
    part[tid] = s1;
    __syncthreads();
    float y1 = 0.f;
    if (half == 0) y1 = tanhf(part[j] + part[j + 256]);
    __syncthreads();
    if (half == 0) h1[j] = y1;
  }
  __syncthreads();
  if (tid < FEAT) {
    float acc = rlb[tid];
    const float4* w = (const float4*)(rlW + (size_t)tid * H_RNN);
    const float4* hv = (const float4*)h1;
#pragma unroll 8
    for (int k = 0; k < 64; ++k) {
      const float4 a = w[k], x = hv[k];
      acc += a.x * x.x + a.y * x.y + a.z * x.z + a.w * x.w;
    }
    emb[(size_t)b * FEAT + tid] = acc;
  }
}

// ---------------------------------------------------------------- rule ranker (pre-sigmoid: monotonic)
__global__ __launch_bounds__(128) void k_ranker(
    const float* __restrict__ emb,
    const float* __restrict__ W1, const float* __restrict__ b1,
    const float* __restrict__ W2, const float* __restrict__ b2,
    const float* __restrict__ W3, const float* __restrict__ b3,
    float* __restrict__ scores) {
  __shared__ float eb[FEAT];
  __shared__ float h1s[128];
  __shared__ float h2s[64];
  const int r = blockIdx.x;
  const int tid = threadIdx.x;
  if (tid < FEAT) eb[tid] = emb[(size_t)r * FEAT + tid];
  __syncthreads();
  {
    float acc = b1[tid];
    const float* w = W1 + (size_t)tid * FEAT;
    for (int k = 0; k < FEAT; ++k) acc += w[k] * eb[k];
    h1s[tid] = acc > 0.f ? acc : 0.f;
  }
  __syncthreads();
  if (tid < 64) {
    float acc = b2[tid];
    const float* w = W2 + (size_t)tid * 128;
    for (int k = 0; k < 128; ++k) acc += w[k] * h1s[k];
    h2s[tid] = acc > 0.f ? acc : 0.f;
  }
  __syncthreads();
  if (tid == 0) {
    float acc = b3[0];
    for (int k = 0; k < 64; ++k) acc += W3[k] * h2s[k];
    scores[r] = acc;   // sigmoid omitted: strictly monotonic, ranking preserved
  }
}

__global__ void k_topk(const float* __restrict__ scores, int* __restrict__ topidx) {
  if (threadIdx.x == 0 && blockIdx.x == 0) {
    float s[N_RULES];
    for (int i = 0; i < N_RULES; ++i) s[i] = scores[i];
    for (int t = 0; t < RULE_NUMS; ++t) {
      int best = 0;
      float bv = s[0];
      for (int i = 1; i < N_RULES; ++i)
        if (s[i] > bv) { bv = s[i]; best = i; }   // strict > : ties -> lowest index (lax.top_k)
      topidx[t] = best;
      s[best] = -1e30f;
    }
  }
}

// ---------------------------------------------------------------- edge message GEMM (MFMA bf16)
// m[e][o] = relu( sum_k [x_dst | e_feat | x_src][k] * linW[o][k] + linB[o] )
__global__ __launch_bounds__(256, 2) void k_msg(
    const u16* __restrict__ xb, const float* __restrict__ ef,
    const int* __restrict__ srcI, const int* __restrict__ dstI,
    const float* __restrict__ linW, const float* __restrict__ linB,
    u16* __restrict__ mOut) {
  __shared__ __align__(16) u16 As[128 * 128];  // 32 KB, rows = edges, swizzled
  __shared__ __align__(16) u16 Bs[128 * 128];  // 32 KB, rows = out cols, swizzled
  const int tid = threadIdx.x;
  const int lane = tid & 63;
  const int wv = tid >> 6;          // 4 waves: 2x2 over (rows, cols)
  const int e0 = blockIdx.x * 128;
  const int rStage = tid >> 1;      // 0..127
  const int hf = tid & 1;

  f32x4 acc[4][4];
  const f32x4 z4 = {0.f, 0.f, 0.f, 0.f};
#pragma unroll
  for (int i = 0; i < 4; ++i)
#pragma unroll
    for (int j = 0; j < 4; ++j) acc[i][j] = z4;

  const int rb = (wv >> 1) * 64;
  const int cb = (wv & 1) * 64;

  for (int c = 0; c < 3; ++c) {   // K-chunks: dst-feat, edge-feat, src-feat
    __syncthreads();
    // ---- stage B: Bs[col][k] = linW[col][c*100+k] (zero-padded to 128x128)
    {
      const float* wrow = linW + (size_t)rStage * 300 + c * 100;
      const bool rowOK = rStage < FEAT;
#pragma unroll
      for (int q = 0; q < 8; ++q) {
        const int cc = hf * 8 + q;
        uint4 v = {0u, 0u, 0u, 0u};
        if (rowOK) {
          const int k0 = cc * 8;
          if (k0 + 8 <= FEAT) {
            const float4 fa = *(const float4*)(wrow + k0);
            const float4 fb = *(const float4*)(wrow + k0 + 4);
            v.x = pk2(fa.x, fa.y); v.y = pk2(fa.z, fa.w);
            v.z = pk2(fb.x, fb.y); v.w = pk2(fb.z, fb.w);
          } else if (k0 < FEAT) {   // k0 == 96
            const float4 fa = *(const float4*)(wrow + k0);
            v.x = pk2(fa.x, fa.y); v.y = pk2(fa.z, fa.w);
          }
        }
        lds_st16(Bs, SWZ(rStage, cc * 16), v);
      }
    }
    // ---- stage A: 128 edge rows of the current K-chunk
    {
      const int eg = e0 + rStage;
      if (c != 1) {
        const int node = (c == 0) ? dstI[eg] : srcI[eg];
        const uint4* xr = (const uint4*)(xb + (size_t)node * XPAD);
#pragma unroll
        for (int q = 0; q < 8; ++q) {
          const int cc = hf * 8 + q;
          uint4 v = {0u, 0u, 0u, 0u};
          if (cc < 14) v = xr[cc];
          lds_st16(As, SWZ(rStage, cc * 16), v);
        }
      } else {
        const float4* er = (const float4*)(ef + (size_t)eg * FEAT);
#pragma unroll
        for (int q = 0; q < 8; ++q) {
          const int cc = hf * 8 + q;
          uint4 v = {0u, 0u, 0u, 0u};
          if (cc <= 12) {
            const float4 fa = er[cc * 2];
            v.x = pk2(fa.x, fa.y); v.y = pk2(fa.z, fa.w);
            if (cc <= 11) {
              const float4 fb = er[cc * 2 + 1];
              v.z = pk2(fb.x, fb.y); v.w = pk2(fb.z, fb.w);
            }
          }
          lds_st16(As, SWZ(rStage, cc * 16), v);
        }
      }
    }
    __syncthreads();
    // ---- MFMA: 4 K-steps of 32
#pragma unroll
    for (int s = 0; s < 4; ++s) {
      const int kByte = s * 64 + ((lane >> 4) << 4);
      short8 af[4], bfr[4];
#pragma unroll
      for (int i = 0; i < 4; ++i) {
        const int row = rb + i * 16 + (lane & 15);
        af[i] = lds_ld16(As, SWZ(row, kByte));
        const int col = cb + i * 16 + (lane & 15);
        bfr[i] = lds_ld16(Bs, SWZ(col, kByte));
      }
#pragma unroll
      for (int i = 0; i < 4; ++i)
#pragma unroll
        for (int j = 0; j < 4; ++j)
          acc[i][j] = __builtin_amdgcn_mfma_f32_16x16x32_bf16(af[i], bfr[j],
                                                              acc[i][j], 0, 0, 0);
    }
  }
  // ---- epilogue: bias + relu + bf16 store
#pragma unroll
  for (int j = 0; j < 4; ++j) {
    const int col = cb + j * 16 + (lane & 15);
    const bool ok = col < FEAT;
    const float bias = ok ? linB[col] : 0.f;
#pragma unroll
    for (int i = 0; i < 4; ++i) {
      const int row0 = rb + i * 16 + ((lane >> 4) << 2);
#pragma unroll
      for (int q = 0; q < 4; ++q) {
        float v = acc[i][j][q] + bias;
        v = v > 0.f ? v : 0.f;
        if (ok) mOut[(size_t)(e0 + row0 + q) * MPAD + col] = f2bu(v);
      }
    }
  }
}

// ---------------------------------------------------------------- node update: CSR gather-sum + residual + MLP + relu
__global__ __launch_bounds__(256) void k_node(
    const u16* __restrict__ mIn, const int* __restrict__ off,
    const int* __restrict__ elist, const float* xin,
    const float* __restrict__ W1, const float* __restrict__ b1,
    const float* __restrict__ W2, const float* __restrict__ b2,
    float* xout, u16* __restrict__ xbout) {
  __shared__ __align__(16) float outb[8][FEAT];
  __shared__ __align__(16) float hb[8][FEAT];
  const int tid = threadIdx.x;
  const int ln = tid >> 5;
  const int j = tid & 31;
  const int n = blockIdx.x * 8 + ln;

  if (j < 25) {
    float a0 = 0.f, a1 = 0.f, a2 = 0.f, a3 = 0.f;
    const int p1 = off[n + 1];
    for (int p = off[n]; p < p1; ++p) {
      const int eid = elist[p];
      const uint2 u = *(const uint2*)(mIn + (size_t)eid * MPAD + j * 4);
      a0 += bu2f((u16)(u.x & 0xffffu));
      a1 += bu2f((u16)(u.x >> 16));
      a2 += bu2f((u16)(u.y & 0xffffu));
      a3 += bu2f((u16)(u.y >> 16));
    }
    const float4 xv = *(const float4*)(xin + (size_t)n * FEAT + j * 4);
    outb[ln][j * 4 + 0] = a0 + xv.x;
    outb[ln][j * 4 + 1] = a1 + xv.y;
    outb[ln][j * 4 + 2] = a2 + xv.z;
    outb[ln][j * 4 + 3] = a3 + xv.w;
  }
  __syncthreads();
#pragma unroll
  for (int tq = 0; tq < 4; ++tq) {
    const int o = j + 32 * tq;
    if (o < FEAT) {
      float acc = b1[o];
      const float4* w4 = (const float4*)(W1 + (size_t)o * FEAT);
      const float4* x4 = (const float4*)(&outb[ln][0]);
#pragma unroll 5
      for (int k = 0; k < 25; ++k) {
        const float4 a = w4[k], x = x4[k];
        acc += a.x * x.x + a.y * x.y + a.z * x.z + a.w * x.w;
      }
      hb[ln][o] = acc > 0.f ? acc : 0.f;
    }
  }
  __syncthreads();
#pragma unroll
  for (int tq = 0; tq < 4; ++tq) {
    const int o = j + 32 * tq;
    if (o < FEAT) {
      float acc = b2[o];
      const float4* w4 = (const float4*)(W2 + (size_t)o * FEAT);
      const float4* x4 = (const float4*)(&hb[ln][0]);
#pragma unroll 5
      for (int k = 0; k < 25; ++k) {
        const float4 a = w4[k], x = x4[k];
        acc += a.x * x.x + a.y * x.y + a.z * x.z + a.w * x.w;
      }
      const float v = acc > 0.f ? acc : 0.f;   // outer relu of _conv_pass
      xout[(size_t)n * FEAT + o] = v;
      xbout[(size_t)n * XPAD + o] = f2bu(v);
    }
  }
}

// ---------------------------------------------------------------- global add pool
__global__ void k_pool(const float* __restrict__ x, float* __restrict__ g) {
  const int tid = threadIdx.x;
  if (tid >= FEAT) return;
  float s = 0.f;
  const int n0 = blockIdx.x * 100;
  for (int i = 0; i < 100; ++i) s += x[(size_t)(n0 + i) * FEAT + tid];
  atomicAdd(&g[tid], s);
}

// ---------------------------------------------------------------- NTN bilinear term
__global__ __launch_bounds__(256) void k_ntn(const float* __restrict__ W,
                                             const float* __restrict__ g1,
                                             const float* __restrict__ g2,
                                             float* __restrict__ tp) {
  __shared__ float g2s[FEAT];
  const int i = blockIdx.x;
  const int tid = threadIdx.x;
  if (tid < FEAT) g2s[tid] = g2[tid];
  __syncthreads();
  if (tid < NTN_OUT) {
    const float g1i = g1[i];
    float acc = 0.f;
    const float* wr = W + (size_t)i * FEAT * NTN_OUT + tid;
    for (int jj = 0; jj < FEAT; ++jj) acc += wr[(size_t)jj * NTN_OUT] * g2s[jj];
    atomicAdd(&tp[tid], g1i * acc);
  }
}

// ---------------------------------------------------------------- scoring head
__global__ __launch_bounds__(512) void k_head(
    const float* __restrict__ tp, const float* __restrict__ gv,
    const float* __restrict__ V, const float* __restrict__ B,
    const float* __restrict__ emb, const int* __restrict__ topidx,
    const float* __restrict__ fc1W, const float* __restrict__ fc1b,
    const float* __restrict__ fc2W, const float* __restrict__ fc2b,
    const float* __restrict__ fc3W, const float* __restrict__ fc3b,
    float* __restrict__ out) {
  __shared__ __align__(16) float feat[NTN_OUT + RULE_NUMS * FEAT];  // 1800
  __shared__ __align__(16) float z1[500];
  __shared__ float z2[FEAT];
  const int tid = threadIdx.x;
  if (tid < NTN_OUT) {
    float acc = B[tid] + tp[tid];
    const float* vr = V + (size_t)tid * 200;
    for (int k = 0; k < FEAT; ++k) acc += vr[k] * gv[k];               // g1
    for (int k = 0; k < FEAT; ++k) acc += vr[FEAT + k] * gv[FEAT + k]; // g2
    feat[tid] = acc > 0.f ? acc : 0.f;
  }
  for (int i = tid; i < RULE_NUMS * FEAT; i += blockDim.x) {
    const int rr = i / FEAT;
    const int cc = i - rr * FEAT;
    feat[NTN_OUT + i] = emb[(size_t)topidx[rr] * FEAT + cc];
  }
  __syncthreads();
  if (tid < 500) {
    float acc = fc1b[tid];
    const float4* w4 = (const float4*)(fc1W + (size_t)tid * 1800);
    const float4* f4 = (const float4*)feat;
    for (int k = 0; k < 450; ++k) {
      const float4 a = w4[k], x = f4[k];
      acc += a.x * x.x + a.y * x.y + a.z * x.z + a.w * x.w;
    }
    z1[tid] = acc > 0.f ? acc : 0.f;
  }
  __syncthreads();
  if (tid < FEAT) {
    float acc = fc2b[tid];
    const float4* w4 = (const float4*)(fc2W + (size_t)tid * 500);
    const float4* f4 = (const float4*)z1;
    for (int k = 0; k < 125; ++k) {
      const float4 a = w4[k], x = f4[k];
      acc += a.x * x.x + a.y * x.y + a.z * x.z + a.w * x.w;
    }
    z2[tid] = acc > 0.f ? acc : 0.f;
  }
  __syncthreads();
  if (tid == 0) {
    float acc = fc3b[0];
    for (int k = 0; k < FEAT; ++k) acc += fc3W[k] * z2[k];
    out[0] = 1.f / (1.f + expf(-acc));
  }
}

// ================================================================ launch
extern "C" void kernel_launch(void* const* d_in, const int* in_sizes, int n_in,
                              void* d_out, int out_size, void* d_ws, size_t ws_size,
                              hipStream_t stream) {
  (void)in_sizes; (void)n_in; (void)out_size; (void)ws_size;

  const float* nf[2] = {(const float*)d_in[0], (const float*)d_in[1]};
  const int* ei[2] = {(const int*)d_in[2], (const int*)d_in[3]};
  const float* ef[2] = {(const float*)d_in[4], (const float*)d_in[5]};
  const float* rules = (const float*)d_in[6];
  const float* cw[2][6];
  for (int l = 0; l < 2; ++l)
    for (int k = 0; k < 6; ++k) cw[l][k] = (const float*)d_in[7 + l * 6 + k];
  const float* ntnW = (const float*)d_in[19];
  const float* ntnV = (const float*)d_in[20];
  const float* ntnB = (const float*)d_in[21];
  const float* r0Wih = (const float*)d_in[22];
  const float* r0Whh = (const float*)d_in[23];
  const float* r0bih = (const float*)d_in[24];
  const float* r0bhh = (const float*)d_in[25];
  const float* r1Wih = (const float*)d_in[26];
  const float* r1Whh = (const float*)d_in[27];
  const float* r1bih = (const float*)d_in[28];
  const float* r1bhh = (const float*)d_in[29];
  const float* rlW = (const float*)d_in[30];
  const float* rlb = (const float*)d_in[31];
  const float* rkW1 = (const float*)d_in[32];
  const float* rkb1 = (const float*)d_in[33];
  const float* rkW2 = (const float*)d_in[34];
  const float* rkb2 = (const float*)d_in[35];
  const float* rkW3 = (const float*)d_in[36];
  const float* rkb3 = (const float*)d_in[37];
  const float* fc1W = (const float*)d_in[38];
  const float* fc1b = (const float*)d_in[39];
  const float* fc2W = (const float*)d_in[40];
  const float* fc2b = (const float*)d_in[41];
  const float* fc3W = (const float*)d_in[42];
  const float* fc3b = (const float*)d_in[43];

  // ---- workspace layout (~94 MB)
  char* base = (char*)d_ws;
  size_t woff = 0;
#define WS_ALLOC(T, NAME, BYTES) \
  T* NAME = (T*)(base + woff);   \
  woff = (woff + (size_t)(BYTES) + 255) & ~(size_t)255;
  WS_ALLOC(u16, m_buf, (size_t)N_EDGES * MPAD * 2)
  WS_ALLOC(u16, xb0, (size_t)N_NODES * XPAD * 2)
  WS_ALLOC(u16, xb1, (size_t)N_NODES * XPAD * 2)
  WS_ALLOC(float, xf0, (size_t)N_NODES * FEAT * 4)
  WS_ALLOC(float, xf1, (size_t)N_NODES * FEAT * 4)
  WS_ALLOC(int, off0, (size_t)(N_NODES + 1) * 4)
  WS_ALLOC(int, off1, (size_t)(N_NODES + 1) * 4)
  WS_ALLOC(int, cursor, (size_t)2 * N_NODES * 4)
  WS_ALLOC(int, el0, (size_t)N_EDGES * 4)
  WS_ALLOC(int, el1, (size_t)N_EDGES * 4)
  WS_ALLOC(float, emb, (size_t)N_RULES * FEAT * 4)
  WS_ALLOC(float, scores, (size_t)N_RULES * 4)
  WS_ALLOC(int, topidx, (size_t)RULE_NUMS * 4)
  WS_ALLOC(float, gtp, (size_t)(2 * FEAT + NTN_OUT) * 4)
#undef WS_ALLOC
  u16* xb[2] = {xb0, xb1};
  float* xf[2] = {xf0, xf1};
  int* csr_off[2] = {off0, off1};
  int* cur[2] = {cursor, cursor + N_NODES};
  int* elist[2] = {el0, el1};
  float* gv = gtp;           // g1[100], g2[100]
  float* tp = gtp + 200;     // tp[200]

  // ---- zero accumulators (ws is poisoned once, never re-poisoned)
  hipMemsetAsync(cursor, 0, (size_t)2 * N_NODES * 4, stream);
  hipMemsetAsync(gtp, 0, (size_t)(2 * FEAT + NTN_OUT) * 4, stream);

  // ---- bf16 mirrors of initial node features
  k_prep<<<2048, 256, 0, stream>>>(nf[0], nf[1], xb[0], xb[1]);

  // ---- CSR per graph
  for (int g = 0; g < 2; ++g) {
    const int* dstp = ei[g] + N_EDGES;
    k_count<<<1250, 256, 0, stream>>>(dstp, cur[g]);
    k_scan<<<1, 1024, 0, stream>>>(cur[g], csr_off[g]);
    k_scatter<<<1250, 256, 0, stream>>>(dstp, cur[g], elist[g]);
  }

  // ---- rule embedding + ranking + topk (pure fp32)
  k_rnn<<<N_RULES, 512, 0, stream>>>(rules, r0Wih, r0Whh, r0bih, r0bhh, r1Wih,
                                     r1Whh, r1bih, r1bhh, rlW, rlb, emb);
  k_ranker<<<N_RULES, 128, 0, stream>>>(emb, rkW1, rkb1, rkW2, rkb2, rkW3, rkb3,
                                        scores);
  k_topk<<<1, 64, 0, stream>>>(scores, topidx);

  // ---- GNN: 2 graphs x 2 TripleConvs
  for (int g = 0; g < 2; ++g) {
    const int* srcp = ei[g];
    const int* dstp = ei[g] + N_EDGES;
    // conv 1 (c1 weights), input = raw node features
    k_msg<<<2500, 256, 0, stream>>>(xb[g], ef[g], srcp, dstp, cw[0][0], cw[0][1],
                                    m_buf);
    k_node<<<2500, 256, 0, stream>>>(m_buf, csr_off[g], elist[g], nf[g], cw[0][2],
                                     cw[0][3], cw[0][4], cw[0][5], xf[g], xb[g]);
    // conv 2 (c2 weights), input = conv1 output (in-place)
    k_msg<<<2500, 256, 0, stream>>>(xb[g], ef[g], srcp, dstp, cw[1][0], cw[1][1],
                                    m_buf);
    k_node<<<2500, 256, 0, stream>>>(m_buf, csr_off[g], elist[g], xf[g], cw[1][2],
                                     cw[1][3], cw[1][4], cw[1][5], xf[g], xb[g]);
    // global add pool
    k_pool<<<200, 128, 0, stream>>>(xf[g], gv + g * FEAT);
  }

  // ---- NTN + head
  k_ntn<<<FEAT, 256, 0, stream>>>(ntnW, gv, gv + FEAT, tp);
  k_head<<<1, 512, 0, stream>>>(tp, gv, ntnV, ntnB, emb, topidx, fc1W, fc1b, fc2W,
                                fc2b, fc3W, fc3b, (float*)d_out);
}

// Round 2
// 1366.392 us; speedup vs baseline: 1.8346x; 1.8346x over previous
//
#include <hip/hip_runtime.h>

typedef unsigned short u16;
typedef unsigned int u32;

#define N_NODES 20000
#define N_EDGES 320000
#define FEAT 100
#define XPAD 112   // padded cols for bf16 node mirrors (14 x 16B rows)
#define MPAD 104   // padded cols for bf16 message buffer (13 x 16B rows)
#define N_RULES 64
#define T_RULE 50
#define H_RNN 256
#define RULE_NUMS 16
#define NTN_OUT 200

typedef __attribute__((ext_vector_type(8))) short short8;
typedef __attribute__((ext_vector_type(4))) float f32x4;

__device__ __forceinline__ u16 f2bu(float f) {
  u32 u = __float_as_uint(f);
  u32 r = (u + 0x7fffu + ((u >> 16) & 1u)) >> 16;   // RNE
  return (u16)r;
}
__device__ __forceinline__ float bu2f(u16 u) {
  return __uint_as_float(((u32)u) << 16);
}
__device__ __forceinline__ u32 pk2(float a, float b) {
  return (u32)f2bu(a) | ((u32)f2bu(b) << 16);
}

__device__ __forceinline__ void lds_st16(void* base, int byteOff, uint4 v) {
  *(uint4*)((char*)base + byteOff) = v;
}
__device__ __forceinline__ short8 lds_ld16(const void* base, int byteOff) {
  return *(const short8*)((const char*)base + byteOff);
}

// XOR swizzle: rows of 256B (128 bf16), flip bits 4..6 by row&7 (G4 / T2)
#define SWZ(row, kByte) (((((row) << 8) + (kByte))) ^ (((row) & 7) << 4))

// H-state LDS swizzle (rows of 512B = 256 bf16): chunk' = (chunk + 5*row) & 31
// -> conflict-free for both the A-fragment read and the per-element write-back.
__device__ __forceinline__ int hs_off(int row, int chunk) {
  return (row << 9) | (((chunk + row * 5) & 31) << 4);
}

__device__ __forceinline__ float tanh_fast(float x) {
  // tanh(x) = 1 - 2/(exp(2x)+1); saturates correctly for |x| large
  const float e = __expf(2.f * x);
  return 1.f - 2.f / (e + 1.f);
}

// ---------------------------------------------------------------- prep: bf16 mirrors
__global__ void k_prep(const float* __restrict__ nf0, const float* __restrict__ nf1,
                       u16* __restrict__ xb0, u16* __restrict__ xb1) {
  const int total = N_NODES * XPAD;
  for (int i = blockIdx.x * blockDim.x + threadIdx.x; i < total;
       i += gridDim.x * blockDim.x) {
    const int n = i / XPAD;
    const int c = i - n * XPAD;
    const float v0 = (c < FEAT) ? nf0[(size_t)n * FEAT + c] : 0.f;
    const float v1 = (c < FEAT) ? nf1[(size_t)n * FEAT + c] : 0.f;
    xb0[i] = f2bu(v0);
    xb1[i] = f2bu(v1);
  }
}

// ---------------------------------------------------------------- CSR build
__global__ void k_count(const int* __restrict__ dstI, int* __restrict__ cnt) {
  const int e = blockIdx.x * blockDim.x + threadIdx.x;
  if (e < N_EDGES) atomicAdd(&cnt[dstI[e]], 1);
}

__global__ __launch_bounds__(1024) void k_scan(int* cnt /*in: counts, out: cursor*/,
                                               int* off) {
  __shared__ int buf[1024];
  __shared__ int carry;
  const int tid = threadIdx.x;
  if (tid == 0) carry = 0;
  __syncthreads();
  for (int base = 0; base < N_NODES; base += 1024) {
    const int i = base + tid;
    const int v = (i < N_NODES) ? cnt[i] : 0;
    buf[tid] = v;
    __syncthreads();
    for (int ofs = 1; ofs < 1024; ofs <<= 1) {
      const int t = (tid >= ofs) ? buf[tid - ofs] : 0;
      __syncthreads();
      buf[tid] += t;
      __syncthreads();
    }
    const int incl = buf[tid];
    const int chunkTotal = buf[1023];
    const int cb = carry;
    __syncthreads();
    if (i < N_NODES) {
      const int excl = cb + incl - v;
      off[i] = excl;
      cnt[i] = excl;   // cursor for scatter
    }
    if (tid == 0) carry = cb + chunkTotal;
    __syncthreads();
  }
  if (tid == 0) off[N_NODES] = carry;
}

__global__ void k_scatter(const int* __restrict__ dstI, int* __restrict__ cursor,
                          int* __restrict__ elist) {
  const int e = blockIdx.x * blockDim.x + threadIdx.x;
  if (e < N_EDGES) {
    const int pos = atomicAdd(&cursor[dstI[e]], 1);
    elist[pos] = e;
  }
}

// ---------------------------------------------------------------- RNN input-GEMM
// U[m][j] = bih[j] + bhh[j] + sum_k A[m][k] * W[j][k],  m = t*64 + r (3200 rows)
// VARIANT 0: A row m <- rules[r][t][0:100] (fp32, K=100 padded to 128)
// VARIANT 1: A row m <- ys[m][0:256]      (bf16, K=256, two 128-phases)
template <int VARIANT>
__global__ __launch_bounds__(256) void k_gemm_u(
    const float* __restrict__ Af, const u16* __restrict__ Ab,
    const float* __restrict__ W, const float* __restrict__ b0,
    const float* __restrict__ b1, float* __restrict__ Uout) {
  __shared__ __align__(16) u16 As[64 * 128];   // 16 KB
  __shared__ __align__(16) u16 Bs[128 * 128];  // 32 KB
  const int tid = threadIdx.x;
  const int lane = tid & 63;
  const int wv = tid >> 6;
  const int l15 = lane & 15;
  const int lhi = lane >> 4;
  const int mb = blockIdx.x * 64;
  const int nb = blockIdx.y * 128;
  const int rb = (wv >> 1) * 32;
  const int cb = (wv & 1) * 64;
  constexpr int KV = VARIANT ? 256 : 100;       // valid K
  constexpr int NPH = VARIANT ? 2 : 1;          // 128-wide K phases

  f32x4 acc[2][4];
  const f32x4 z4 = {0.f, 0.f, 0.f, 0.f};
#pragma unroll
  for (int i = 0; i < 2; ++i)
#pragma unroll
    for (int j = 0; j < 4; ++j) acc[i][j] = z4;

  for (int kc = 0; kc < NPH; ++kc) {
    __syncthreads();
    // ---- stage A (64 rows x 128 local-k): thread -> row tid>>2, k-span 32
    {
      const int row = tid >> 2;
      const int k0 = (tid & 3) * 32;
      const int gm = mb + row;
      if (VARIANT == 0) {
        const int r = gm & 63;
        const int t = gm >> 6;
        const float* ar = Af + ((size_t)r * T_RULE + t) * FEAT;
#pragma unroll
        for (int c = 0; c < 4; ++c) {
          const int k = k0 + c * 8;
          uint4 v = {0u, 0u, 0u, 0u};
          if (k + 8 <= KV) {
            const float4 fa = *(const float4*)(ar + k);
            const float4 fb = *(const float4*)(ar + k + 4);
            v.x = pk2(fa.x, fa.y); v.y = pk2(fa.z, fa.w);
            v.z = pk2(fb.x, fb.y); v.w = pk2(fb.z, fb.w);
          } else if (k < KV) {   // k == 96: 4 valid
            const float4 fa = *(const float4*)(ar + k);
            v.x = pk2(fa.x, fa.y); v.y = pk2(fa.z, fa.w);
          }
          lds_st16(As, SWZ(row, k * 2), v);
        }
      } else {
        const uint4* ar = (const uint4*)(Ab + (size_t)gm * 256 + kc * 128 + k0);
#pragma unroll
        for (int c = 0; c < 4; ++c)
          lds_st16(As, SWZ(row, (k0 + c * 8) * 2), ar[c]);
      }
    }
    // ---- stage B (128 N-rows x 128 local-k): thread -> row tid>>1, k-span 64
    {
      const int row = tid >> 1;
      const int k0 = (tid & 1) * 64;
      const float* wr = W + (size_t)(nb + row) * KV;
#pragma unroll
      for (int c = 0; c < 8; ++c) {
        const int k = k0 + c * 8;
        const int kg = kc * 128 + k;
        uint4 v = {0u, 0u, 0u, 0u};
        if (kg + 8 <= KV) {
          const float4 fa = *(const float4*)(wr + kg);
          const float4 fb = *(const float4*)(wr + kg + 4);
          v.x = pk2(fa.x, fa.y); v.y = pk2(fa.z, fa.w);
          v.z = pk2(fb.x, fb.y); v.w = pk2(fb.z, fb.w);
        } else if (kg < KV) {
          const float4 fa = *(const float4*)(wr + kg);
          v.x = pk2(fa.x, fa.y); v.y = pk2(fa.z, fa.w);
        }
        lds_st16(Bs, SWZ(row, k * 2), v);
      }
    }
    __syncthreads();
#pragma unroll
    for (int s = 0; s < 4; ++s) {
      const int kByte = s * 64 + lhi * 16;
      short8 af[2], bfr[4];
#pragma unroll
      for (int i = 0; i < 2; ++i)
        af[i] = lds_ld16(As, SWZ(rb + i * 16 + l15, kByte));
#pragma unroll
      for (int j = 0; j < 4; ++j)
        bfr[j] = lds_ld16(Bs, SWZ(cb + j * 16 + l15, kByte));
#pragma unroll
      for (int i = 0; i < 2; ++i)
#pragma unroll
        for (int j = 0; j < 4; ++j)
          acc[i][j] = __builtin_amdgcn_mfma_f32_16x16x32_bf16(af[i], bfr[j],
                                                              acc[i][j], 0, 0, 0);
    }
  }
  // ---- epilogue: + (bih + bhh)
#pragma unroll
  for (int j = 0; j < 4; ++j) {
    const int col = nb + cb + j * 16 + l15;
    const float bias = b0[col] + b1[col];
#pragma unroll
    for (int i = 0; i < 2; ++i) {
      const int m0 = mb + rb + i * 16 + lhi * 4;
#pragma unroll
      for (int q = 0; q < 4; ++q)
        Uout[(size_t)(m0 + q) * 256 + col] = acc[i][j][q] + bias;
    }
  }
}

// ---------------------------------------------------------------- RNN recurrence
// Per block: 16 rules. H[16,256] = tanh(U[t] + H @ Whh^T), Whh B-frags in regs.
template <int WRITE_YS>
__global__ __launch_bounds__(512) void k_rec(
    const float* __restrict__ U,    // [50][64][256]
    const float* __restrict__ Whh,  // [256][256] fp32
    u16* __restrict__ ys,           // [50][64][256] bf16 (WRITE_YS)
    float* __restrict__ hT) {       // [64][256] fp32 (!WRITE_YS)
  __shared__ __align__(16) u16 Hs[16 * 256];   // 8 KB
  const int tid = threadIdx.x;
  const int lane = tid & 63;
  const int wv = tid >> 6;          // 8 waves -> 32 cols each
  const int cbase = wv * 32;
  const int ruleBase = blockIdx.x * 16;
  const int l15 = lane & 15;
  const int lhi = lane >> 4;

  // ---- Whh B-fragments -> registers (held across all 50 steps)
  short8 bf[2][8];
#pragma unroll
  for (int jt = 0; jt < 2; ++jt) {
    const int col = cbase + jt * 16 + l15;
    const float* wr = Whh + (size_t)col * 256;
#pragma unroll
    for (int s = 0; s < 8; ++s) {
      const int k0 = s * 32 + lhi * 8;
      const float4 fa = *(const float4*)(wr + k0);
      const float4 fb = *(const float4*)(wr + k0 + 4);
      uint4 v;
      v.x = pk2(fa.x, fa.y); v.y = pk2(fa.z, fa.w);
      v.z = pk2(fb.x, fb.y); v.w = pk2(fb.z, fb.w);
      bf[jt][s] = *(short8*)&v;
    }
  }
  // ---- H = 0
  for (int i = tid; i < 16 * 256 / 8; i += 512) {
    const uint4 z = {0u, 0u, 0u, 0u};
    ((uint4*)Hs)[i] = z;
  }
  __syncthreads();

  const f32x4 z4 = {0.f, 0.f, 0.f, 0.f};
  float hv[2][4];
  for (int t = 0; t < T_RULE; ++t) {
    f32x4 acc[2] = {z4, z4};
#pragma unroll
    for (int s = 0; s < 8; ++s) {
      const short8 af = lds_ld16(Hs, hs_off(l15, s * 4 + lhi));
#pragma unroll
      for (int jt = 0; jt < 2; ++jt)
        acc[jt] = __builtin_amdgcn_mfma_f32_16x16x32_bf16(af, bf[jt][s],
                                                          acc[jt], 0, 0, 0);
    }
    const float* Ut = U + ((size_t)t * 64 + ruleBase) * 256;
#pragma unroll
    for (int jt = 0; jt < 2; ++jt) {
      const int n = cbase + jt * 16 + l15;
#pragma unroll
      for (int q = 0; q < 4; ++q) {
        const int m = lhi * 4 + q;
        hv[jt][q] = tanh_fast(Ut[(size_t)m * 256 + n] + acc[jt][q]);
      }
    }
    __syncthreads();   // all Hs reads done before overwrite
#pragma unroll
    for (int jt = 0; jt < 2; ++jt) {
      const int n = cbase + jt * 16 + l15;
#pragma unroll
      for (int q = 0; q < 4; ++q) {
        const int m = lhi * 4 + q;
        const u16 hb = f2bu(hv[jt][q]);
        *(u16*)((char*)Hs + (hs_off(m, n >> 3) + ((n & 7) << 1))) = hb;
        if (WRITE_YS)
          ys[(((size_t)t * 64 + ruleBase + m) << 8) + n] = hb;
      }
    }
    __syncthreads();
  }
  if (!WRITE_YS) {
#pragma unroll
    for (int jt = 0; jt < 2; ++jt) {
      const int n = cbase + jt * 16 + l15;
#pragma unroll
      for (int q = 0; q < 4; ++q) {
        const int m = lhi * 4 + q;
        hT[((size_t)(ruleBase + m) << 8) + n] = hv[jt][q];
      }
    }
  }
}

// ---------------------------------------------------------------- rule linear: emb = hT @ rlW^T + rlb
__global__ __launch_bounds__(128) void k_rulelin(
    const float* __restrict__ hT, const float* __restrict__ rlW,
    const float* __restrict__ rlb, float* __restrict__ emb) {
  __shared__ __align__(16) float hs[H_RNN];
  const int b = blockIdx.x;
  const int tid = threadIdx.x;
  for (int i = tid; i < H_RNN / 4; i += 128)
    ((float4*)hs)[i] = ((const float4*)(hT + (size_t)b * H_RNN))[i];
  __syncthreads();
  if (tid < FEAT) {
    float acc = rlb[tid];
    const float4* w = (const float4*)(rlW + (size_t)tid * H_RNN);
    const float4* hv = (const float4*)hs;
#pragma unroll 8
    for (int k = 0; k < 64; ++k) {
      const float4 a = w[k], x = hv[k];
      acc += a.x * x.x + a.y * x.y + a.z * x.z + a.w * x.w;
    }
    emb[(size_t)b * FEAT + tid] = acc;
  }
}

// ---------------------------------------------------------------- rule ranker (pre-sigmoid: monotonic)
__global__ __launch_bounds__(128) void k_ranker(
    const float* __restrict__ emb,
    const float* __restrict__ W1, const float* __restrict__ b1,
    const float* __restrict__ W2, const float* __restrict__ b2,
    const float* __restrict__ W3, const float* __restrict__ b3,
    float* __restrict__ scores) {
  __shared__ float eb[FEAT];
  __shared__ float h1s[128];
  __shared__ float h2s[64];
  const int r = blockIdx.x;
  const int tid = threadIdx.x;
  if (tid < FEAT) eb[tid] = emb[(size_t)r * FEAT + tid];
  __syncthreads();
  {
    float acc = b1[tid];
    const float* w = W1 + (size_t)tid * FEAT;
    for (int k = 0; k < FEAT; ++k) acc += w[k] * eb[k];
    h1s[tid] = acc > 0.f ? acc : 0.f;
  }
  __syncthreads();
  if (tid < 64) {
    float acc = b2[tid];
    const float* w = W2 + (size_t)tid * 128;
    for (int k = 0; k < 128; ++k) acc += w[k] * h1s[k];
    h2s[tid] = acc > 0.f ? acc : 0.f;
  }
  __syncthreads();
  if (tid == 0) {
    float acc = b3[0];
    for (int k = 0; k < 64; ++k) acc += W3[k] * h2s[k];
    scores[r] = acc;   // sigmoid omitted: strictly monotonic, ranking preserved
  }
}

__global__ void k_topk(const float* __restrict__ scores, int* __restrict__ topidx) {
  if (threadIdx.x == 0 && blockIdx.x == 0) {
    float s[N_RULES];
    for (int i = 0; i < N_RULES; ++i) s[i] = scores[i];
    for (int t = 0; t < RULE_NUMS; ++t) {
      int best = 0;
      float bv = s[0];
      for (int i = 1; i < N_RULES; ++i)
        if (s[i] > bv) { bv = s[i]; best = i; }   // strict > : ties -> lowest index
      topidx[t] = best;
      s[best] = -1e30f;
    }
  }
}

// ---------------------------------------------------------------- edge message GEMM (MFMA bf16)
// m[e][o] = relu( sum_k [x_dst | e_feat | x_src][k] * linW[o][k] + linB[o] )
__global__ __launch_bounds__(256, 2) void k_msg(
    const u16* __restrict__ xb, const float* __restrict__ ef,
    const int* __restrict__ srcI, const int* __restrict__ dstI,
    const float* __restrict__ linW, const float* __restrict__ linB,
    u16* __restrict__ mOut) {
  __shared__ __align__(16) u16 As[128 * 128];  // 32 KB, rows = edges, swizzled
  __shared__ __align__(16) u16 Bs[128 * 128];  // 32 KB, rows = out cols, swizzled
  const int tid = threadIdx.x;
  const int lane = tid & 63;
  const int wv = tid >> 6;          // 4 waves: 2x2 over (rows, cols)
  const int e0 = blockIdx.x * 128;
  const int rStage = tid >> 1;      // 0..127
  const int hf = tid & 1;

  f32x4 acc[4][4];
  const f32x4 z4 = {0.f, 0.f, 0.f, 0.f};
#pragma unroll
  for (int i = 0; i < 4; ++i)
#pragma unroll
    for (int j = 0; j < 4; ++j) acc[i][j] = z4;

  const int rb = (wv >> 1) * 64;
  const int cb = (wv & 1) * 64;

  for (int c = 0; c < 3; ++c) {   // K-chunks: dst-feat, edge-feat, src-feat
    __syncthreads();
    // ---- stage B: Bs[col][k] = linW[col][c*100+k] (zero-padded to 128x128)
    {
      const float* wrow = linW + (size_t)rStage * 300 + c * 100;
      const bool rowOK = rStage < FEAT;
#pragma unroll
      for (int q = 0; q < 8; ++q) {
        const int cc = hf * 8 + q;
        uint4 v = {0u, 0u, 0u, 0u};
        if (rowOK) {
          const int k0 = cc * 8;
          if (k0 + 8 <= FEAT) {
            const float4 fa = *(const float4*)(wrow + k0);
            const float4 fb = *(const float4*)(wrow + k0 + 4);
            v.x = pk2(fa.x, fa.y); v.y = pk2(fa.z, fa.w);
            v.z = pk2(fb.x, fb.y); v.w = pk2(fb.z, fb.w);
          } else if (k0 < FEAT) {   // k0 == 96
            const float4 fa = *(const float4*)(wrow + k0);
            v.x = pk2(fa.x, fa.y); v.y = pk2(fa.z, fa.w);
          }
        }
        lds_st16(Bs, SWZ(rStage, cc * 16), v);
      }
    }
    // ---- stage A: 128 edge rows of the current K-chunk
    {
      const int eg = e0 + rStage;
      if (c != 1) {
        const int node = (c == 0) ? dstI[eg] : srcI[eg];
        const uint4* xr = (const uint4*)(xb + (size_t)node * XPAD);
#pragma unroll
        for (int q = 0; q < 8; ++q) {
          const int cc = hf * 8 + q;
          uint4 v = {0u, 0u, 0u, 0u};
          if (cc < 14) v = xr[cc];
          lds_st16(As, SWZ(rStage, cc * 16), v);
        }
      } else {
        const float4* er = (const float4*)(ef + (size_t)eg * FEAT);
#pragma unroll
        for (int q = 0; q < 8; ++q) {
          const int cc = hf * 8 + q;
          uint4 v = {0u, 0u, 0u, 0u};
          if (cc <= 12) {
            const float4 fa = er[cc * 2];
            v.x = pk2(fa.x, fa.y); v.y = pk2(fa.z, fa.w);
            if (cc <= 11) {
              const float4 fb = er[cc * 2 + 1];
              v.z = pk2(fb.x, fb.y); v.w = pk2(fb.z, fb.w);
            }
          }
          lds_st16(As, SWZ(rStage, cc * 16), v);
        }
      }
    }
    __syncthreads();
    // ---- MFMA: 4 K-steps of 32
#pragma unroll
    for (int s = 0; s < 4; ++s) {
      const int kByte = s * 64 + ((lane >> 4) << 4);
      short8 af[4], bfr[4];
#pragma unroll
      for (int i = 0; i < 4; ++i) {
        const int row = rb + i * 16 + (lane & 15);
        af[i] = lds_ld16(As, SWZ(row, kByte));
        const int col = cb + i * 16 + (lane & 15);
        bfr[i] = lds_ld16(Bs, SWZ(col, kByte));
      }
#pragma unroll
      for (int i = 0; i < 4; ++i)
#pragma unroll
        for (int j = 0; j < 4; ++j)
          acc[i][j] = __builtin_amdgcn_mfma_f32_16x16x32_bf16(af[i], bfr[j],
                                                              acc[i][j], 0, 0, 0);
    }
  }
  // ---- epilogue: bias + relu + bf16 store
#pragma unroll
  for (int j = 0; j < 4; ++j) {
    const int col = cb + j * 16 + (lane & 15);
    const bool ok = col < FEAT;
    const float bias = ok ? linB[col] : 0.f;
#pragma unroll
    for (int i = 0; i < 4; ++i) {
      const int row0 = rb + i * 16 + ((lane >> 4) << 2);
#pragma unroll
      for (int q = 0; q < 4; ++q) {
        float v = acc[i][j][q] + bias;
        v = v > 0.f ? v : 0.f;
        if (ok) mOut[(size_t)(e0 + row0 + q) * MPAD + col] = f2bu(v);
      }
    }
  }
}

// ---------------------------------------------------------------- node update: CSR gather-sum + residual + MLP + relu
__global__ __launch_bounds__(256) void k_node(
    const u16* __restrict__ mIn, const int* __restrict__ off,
    const int* __restrict__ elist, const float* xin,
    const float* __restrict__ W1, const float* __restrict__ b1,
    const float* __restrict__ W2, const float* __restrict__ b2,
    float* xout, u16* __restrict__ xbout) {
  __shared__ __align__(16) float outb[8][FEAT];
  __shared__ __align__(16) float hb[8][FEAT];
  const int tid = threadIdx.x;
  const int ln = tid >> 5;
  const int j = tid & 31;
  const int n = blockIdx.x * 8 + ln;

  if (j < 25) {
    float a0 = 0.f, a1 = 0.f, a2 = 0.f, a3 = 0.f;
    const int p1 = off[n + 1];
    for (int p = off[n]; p < p1; ++p) {
      const int eid = elist[p];
      const uint2 u = *(const uint2*)(mIn + (size_t)eid * MPAD + j * 4);
      a0 += bu2f((u16)(u.x & 0xffffu));
      a1 += bu2f((u16)(u.x >> 16));
      a2 += bu2f((u16)(u.y & 0xffffu));
      a3 += bu2f((u16)(u.y >> 16));
    }
    const float4 xv = *(const float4*)(xin + (size_t)n * FEAT + j * 4);
    outb[ln][j * 4 + 0] = a0 + xv.x;
    outb[ln][j * 4 + 1] = a1 + xv.y;
    outb[ln][j * 4 + 2] = a2 + xv.z;
    outb[ln][j * 4 + 3] = a3 + xv.w;
  }
  __syncthreads();
#pragma unroll
  for (int tq = 0; tq < 4; ++tq) {
    const int o = j + 32 * tq;
    if (o < FEAT) {
      float acc = b1[o];
      const float4* w4 = (const float4*)(W1 + (size_t)o * FEAT);
      const float4* x4 = (const float4*)(&outb[ln][0]);
#pragma unroll 5
      for (int k = 0; k < 25; ++k) {
        const float4 a = w4[k], x = x4[k];
        acc += a.x * x.x + a.y * x.y + a.z * x.z + a.w * x.w;
      }
      hb[ln][o] = acc > 0.f ? acc : 0.f;
    }
  }
  __syncthreads();
#pragma unroll
  for (int tq = 0; tq < 4; ++tq) {
    const int o = j + 32 * tq;
    if (o < FEAT) {
      float acc = b2[o];
      const float4* w4 = (const float4*)(W2 + (size_t)o * FEAT);
      const float4* x4 = (const float4*)(&hb[ln][0]);
#pragma unroll 5
      for (int k = 0; k < 25; ++k) {
        const float4 a = w4[k], x = x4[k];
        acc += a.x * x.x + a.y * x.y + a.z * x.z + a.w * x.w;
      }
      const float v = acc > 0.f ? acc : 0.f;   // outer relu of _conv_pass
      xout[(size_t)n * FEAT + o] = v;
      xbout[(size_t)n * XPAD + o] = f2bu(v);
    }
  }
}

// ---------------------------------------------------------------- global add pool
__global__ void k_pool(const float* __restrict__ x, float* __restrict__ g) {
  const int tid = threadIdx.x;
  if (tid >= FEAT) return;
  float s = 0.f;
  const int n0 = blockIdx.x * 100;
  for (int i = 0; i < 100; ++i) s += x[(size_t)(n0 + i) * FEAT + tid];
  atomicAdd(&g[tid], s);
}

// ---------------------------------------------------------------- NTN bilinear term
__global__ __launch_bounds__(256) void k_ntn(const float* __restrict__ W,
                                             const float* __restrict__ g1,
                                             const float* __restrict__ g2,
                                             float* __restrict__ tp) {
  __shared__ float g2s[FEAT];
  const int i = blockIdx.x;
  const int tid = threadIdx.x;
  if (tid < FEAT) g2s[tid] = g2[tid];
  __syncthreads();
  if (tid < NTN_OUT) {
    const float g1i = g1[i];
    float acc = 0.f;
    const float* wr = W + (size_t)i * FEAT * NTN_OUT + tid;
    for (int jj = 0; jj < FEAT; ++jj) acc += wr[(size_t)jj * NTN_OUT] * g2s[jj];
    atomicAdd(&tp[tid], g1i * acc);
  }
}

// ---------------------------------------------------------------- head, split
__global__ __launch_bounds__(256) void k_feat(
    const float* __restrict__ tp, const float* __restrict__ gv,
    const float* __restrict__ V, const float* __restrict__ B,
    const float* __restrict__ emb, const int* __restrict__ topidx,
    float* __restrict__ featOut) {
  const int tid = threadIdx.x;
  if (tid < NTN_OUT) {
    float acc = B[tid] + tp[tid];
    const float* vr = V + (size_t)tid * 200;
    for (int k = 0; k < 200; ++k) acc += vr[k] * gv[k];   // gv = [g1|g2]
    featOut[tid] = acc > 0.f ? acc : 0.f;
  }
  for (int i = tid; i < RULE_NUMS * FEAT; i += 256) {
    const int rr = i / FEAT;
    const int cc = i - rr * FEAT;
    featOut[NTN_OUT + i] = emb[(size_t)topidx[rr] * FEAT + cc];
  }
}

__global__ __launch_bounds__(256) void k_fc1(
    const float* __restrict__ feat, const float* __restrict__ W,
    const float* __restrict__ b, float* __restrict__ z1) {
  __shared__ __align__(16) float fs[NTN_OUT + RULE_NUMS * FEAT];   // 1800
  const int tid = threadIdx.x;
  for (int i = tid; i < 450; i += 256) ((float4*)fs)[i] = ((const float4*)feat)[i];
  __syncthreads();
  const int lane = tid & 63;
  const int wv = tid >> 6;
  const int o = blockIdx.x * 4 + wv;   // grid 125 -> o < 500
  float acc = 0.f;
  const float4* w4 = (const float4*)(W + (size_t)o * 1800);
  const float4* f4 = (const float4*)fs;
  for (int k = lane; k < 450; k += 64) {
    const float4 a = w4[k], x = f4[k];
    acc += a.x * x.x + a.y * x.y + a.z * x.z + a.w * x.w;
  }
#pragma unroll
  for (int d = 32; d; d >>= 1) acc += __shfl_down(acc, d);
  if (lane == 0) {
    acc += b[o];
    z1[o] = acc > 0.f ? acc : 0.f;
  }
}

__global__ __launch_bounds__(128) void k_head2(
    const float* __restrict__ z1g, const float* __restrict__ fc2W,
    const float* __restrict__ fc2b, const float* __restrict__ fc3W,
    const float* __restrict__ fc3b, float* __restrict__ out) {
  __shared__ __align__(16) float z1[500];
  __shared__ float z2[FEAT];
  const int tid = threadIdx.x;
  for (int i = tid; i < 125; i += 128) ((float4*)z1)[i] = ((const float4*)z1g)[i];
  __syncthreads();
  if (tid < FEAT) {
    float acc = fc2b[tid];
    const float4* w4 = (const float4*)(fc2W + (size_t)tid * 500);
    const float4* f4 = (const float4*)z1;
#pragma unroll 5
    for (int k = 0; k < 125; ++k) {
      const float4 a = w4[k], x = f4[k];
      acc += a.x * x.x + a.y * x.y + a.z * x.z + a.w * x.w;
    }
    z2[tid] = acc > 0.f ? acc : 0.f;
  }
  __syncthreads();
  if (tid == 0) {
    float acc = fc3b[0];
    for (int k = 0; k < FEAT; ++k) acc += fc3W[k] * z2[k];
    out[0] = 1.f / (1.f + expf(-acc));
  }
}

// ================================================================ launch
extern "C" void kernel_launch(void* const* d_in, const int* in_sizes, int n_in,
                              void* d_out, int out_size, void* d_ws, size_t ws_size,
                              hipStream_t stream) {
  (void)in_sizes; (void)n_in; (void)out_size; (void)ws_size;

  const float* nf[2] = {(const float*)d_in[0], (const float*)d_in[1]};
  const int* ei[2] = {(const int*)d_in[2], (const int*)d_in[3]};
  const float* ef[2] = {(const float*)d_in[4], (const float*)d_in[5]};
  const float* rules = (const float*)d_in[6];
  const float* cw[2][6];
  for (int l = 0; l < 2; ++l)
    for (int k = 0; k < 6; ++k) cw[l][k] = (const float*)d_in[7 + l * 6 + k];
  const float* ntnW = (const float*)d_in[19];
  const float* ntnV = (const float*)d_in[20];
  const float* ntnB = (const float*)d_in[21];
  const float* r0Wih = (const float*)d_in[22];
  const float* r0Whh = (const float*)d_in[23];
  const float* r0bih = (const float*)d_in[24];
  const float* r0bhh = (const float*)d_in[25];
  const float* r1Wih = (const float*)d_in[26];
  const float* r1Whh = (const float*)d_in[27];
  const float* r1bih = (const float*)d_in[28];
  const float* r1bhh = (const float*)d_in[29];
  const float* rlW = (const float*)d_in[30];
  const float* rlb = (const float*)d_in[31];
  const float* rkW1 = (const float*)d_in[32];
  const float* rkb1 = (const float*)d_in[33];
  const float* rkW2 = (const float*)d_in[34];
  const float* rkb2 = (const float*)d_in[35];
  const float* rkW3 = (const float*)d_in[36];
  const float* rkb3 = (const float*)d_in[37];
  const float* fc1W = (const float*)d_in[38];
  const float* fc1b = (const float*)d_in[39];
  const float* fc2W = (const float*)d_in[40];
  const float* fc2b = (const float*)d_in[41];
  const float* fc3W = (const float*)d_in[42];
  const float* fc3b = (const float*)d_in[43];

  // ---- workspace layout (~94 MB)
  char* base = (char*)d_ws;
  size_t woff = 0;
#define WS_ALLOC(T, NAME, BYTES) \
  T* NAME = (T*)(base + woff);   \
  woff = (woff + (size_t)(BYTES) + 255) & ~(size_t)255;
  WS_ALLOC(u16, m_buf, (size_t)N_EDGES * MPAD * 2)
  WS_ALLOC(u16, xb0, (size_t)N_NODES * XPAD * 2)
  WS_ALLOC(u16, xb1, (size_t)N_NODES * XPAD * 2)
  WS_ALLOC(float, xf0, (size_t)N_NODES * FEAT * 4)
  WS_ALLOC(float, xf1, (size_t)N_NODES * FEAT * 4)
  WS_ALLOC(int, off0, (size_t)(N_NODES + 1) * 4)
  WS_ALLOC(int, off1, (size_t)(N_NODES + 1) * 4)
  WS_ALLOC(int, cursor, (size_t)2 * N_NODES * 4)
  WS_ALLOC(int, el0, (size_t)N_EDGES * 4)
  WS_ALLOC(int, el1, (size_t)N_EDGES * 4)
  WS_ALLOC(float, emb, (size_t)N_RULES * FEAT * 4)
  WS_ALLOC(float, scores, (size_t)N_RULES * 4)
  WS_ALLOC(int, topidx, (size_t)RULE_NUMS * 4)
  WS_ALLOC(float, gtp, (size_t)(2 * FEAT + NTN_OUT) * 4)
#undef WS_ALLOC
  u16* xb[2] = {xb0, xb1};
  float* xf[2] = {xf0, xf1};
  int* csr_off[2] = {off0, off1};
  int* cur[2] = {cursor, cursor + N_NODES};
  int* elist[2] = {el0, el1};
  float* gv = gtp;           // g1[100], g2[100]
  float* tp = gtp + 200;     // tp[200]

  // RNN / head scratch overlaid on m_buf (66 MB; serial stream, lifetimes disjoint):
  //   U[3200][256] f32 (3,276,800 B) | ys[3200][256] bf16 (1,638,400 B) | hT (65,536 B)
  //   feat[1800] f32 | z1[500] f32   (used after GNN phase, m_buf dead by then)
  float* U   = (float*)m_buf;
  u16*   ys  = (u16*)((char*)m_buf + 3276800);
  float* hT  = (float*)((char*)m_buf + 4915200);
  float* featWS = (float*)((char*)m_buf + 4980736);
  float* z1WS   = (float*)((char*)m_buf + 4988160);

  // ---- zero accumulators (ws is poisoned once, never re-poisoned)
  hipMemsetAsync(cursor, 0, (size_t)2 * N_NODES * 4, stream);
  hipMemsetAsync(gtp, 0, (size_t)(2 * FEAT + NTN_OUT) * 4, stream);

  // ---- bf16 mirrors of initial node features
  k_prep<<<2048, 256, 0, stream>>>(nf[0], nf[1], xb[0], xb[1]);

  // ---- CSR per graph
  for (int g = 0; g < 2; ++g) {
    const int* dstp = ei[g] + N_EDGES;
    k_count<<<1250, 256, 0, stream>>>(dstp, cur[g]);
    k_scan<<<1, 1024, 0, stream>>>(cur[g], csr_off[g]);
    k_scatter<<<1250, 256, 0, stream>>>(dstp, cur[g], elist[g]);
  }

  // ---- rule embedding: U0 GEMM -> rec0 -> U1 GEMM -> rec1 -> linear
  {
    dim3 gg(50, 2);
    k_gemm_u<0><<<gg, 256, 0, stream>>>(rules, nullptr, r0Wih, r0bih, r0bhh, U);
    k_rec<1><<<4, 512, 0, stream>>>(U, r0Whh, ys, nullptr);
    k_gemm_u<1><<<gg, 256, 0, stream>>>(nullptr, ys, r1Wih, r1bih, r1bhh, U);
    k_rec<0><<<4, 512, 0, stream>>>(U, r1Whh, nullptr, hT);
    k_rulelin<<<N_RULES, 128, 0, stream>>>(hT, rlW, rlb, emb);
  }
  k_ranker<<<N_RULES, 128, 0, stream>>>(emb, rkW1, rkb1, rkW2, rkb2, rkW3, rkb3,
                                        scores);
  k_topk<<<1, 64, 0, stream>>>(scores, topidx);

  // ---- GNN: 2 graphs x 2 TripleConvs
  for (int g = 0; g < 2; ++g) {
    const int* srcp = ei[g];
    const int* dstp = ei[g] + N_EDGES;
    // conv 1 (c1 weights), input = raw node features
    k_msg<<<2500, 256, 0, stream>>>(xb[g], ef[g], srcp, dstp, cw[0][0], cw[0][1],
                                    m_buf);
    k_node<<<2500, 256, 0, stream>>>(m_buf, csr_off[g], elist[g], nf[g], cw[0][2],
                                     cw[0][3], cw[0][4], cw[0][5], xf[g], xb[g]);
    // conv 2 (c2 weights), input = conv1 output (in-place)
    k_msg<<<2500, 256, 0, stream>>>(xb[g], ef[g], srcp, dstp, cw[1][0], cw[1][1],
                                    m_buf);
    k_node<<<2500, 256, 0, stream>>>(m_buf, csr_off[g], elist[g], xf[g], cw[1][2],
                                     cw[1][3], cw[1][4], cw[1][5], xf[g], xb[g]);
    // global add pool
    k_pool<<<200, 128, 0, stream>>>(xf[g], gv + g * FEAT);
  }

  // ---- NTN + head
  k_ntn<<<FEAT, 256, 0, stream>>>(ntnW, gv, gv + FEAT, tp);
  k_feat<<<1, 256, 0, stream>>>(tp, gv, ntnV, ntnB, emb, topidx, featWS);
  k_fc1<<<125, 256, 0, stream>>>(featWS, fc1W, fc1b, z1WS);
  k_head2<<<1, 128, 0, stream>>>(z1WS, fc2W, fc2b, fc3W, fc3b, (float*)d_out);
}